// Round 8
// baseline (44.731 us; speedup 1.0000x reference)
//
#include <hip/hip_runtime.h>

#pragma clang fp contract(off)

typedef unsigned long long u64;

#define TOPK 5
#define WAVES 4
#define CHUNK 1024   // candidates staged per iteration (4 per thread)

// branchless compare-exchange on u64 keys (ascending)
#define CE(x, y) do { const u64 _a = (x), _b = (y); const bool _l = _b < _a; \
                      (x) = _l ? _b : _a; (y) = _l ? _a : _b; } while (0)

// branchless sorted-insert of nk into ascending 5-list
#define INSERT(nk, k0, k1, k2, k3, k4) do {        \
    const u64 _n = (nk);                           \
    const bool l0 = _n < k0;                       \
    const bool l1 = _n < k1;                       \
    const bool l2 = _n < k2;                       \
    const bool l3 = _n < k3;                       \
    const bool l4 = _n < k4;                       \
    k4 = l4 ? (l3 ? k3 : _n) : k4;                 \
    k3 = l3 ? (l2 ? k2 : _n) : k3;                 \
    k2 = l2 ? (l1 ? k1 : _n) : k2;                 \
    k1 = l1 ? (l0 ? k0 : _n) : k1;                 \
    k0 = l0 ? _n : k0;                             \
} while (0)

// Markstein-refined division (bit-exact vs reference: absmax 0.0 in R3-R7)
__device__ __forceinline__ float fast_div(float a, float b) {
    float r = __builtin_amdgcn_rcpf(b);
    r = fmaf(fmaf(-b, r, 1.0f), r, r);
    float q = a * r;
    q = fmaf(fmaf(-b, q, a), r, q);
    return q;
}

// full cost given precomputed cost_bbox (cb)
__device__ __forceinline__ u64 eval_rest(const float4 pb, const float cb,
                                         const float4 gb, const float g_area,
                                         const int p) {
    const float area_p = (pb.z - pb.x) * (pb.w - pb.y);
    const float ltx = fmaxf(pb.x, gb.x), lty = fmaxf(pb.y, gb.y);
    const float rbx = fminf(pb.z, gb.z), rby = fminf(pb.w, gb.w);
    const float iw = fmaxf(rbx - ltx, 0.0f), ih = fmaxf(rby - lty, 0.0f);
    const float inter = iw * ih;
    const float uni = area_p + g_area - inter;
    const float iou = fast_div(inter, uni);
    const float ex1 = fminf(pb.x, gb.x), ey1 = fminf(pb.y, gb.y);
    const float ex2 = fmaxf(pb.z, gb.z), ey2 = fmaxf(pb.w, gb.w);
    const float area_e = (ex2 - ex1) * (ey2 - ey1);
    const float giou = iou - fast_div(area_e - uni, area_e);
    const float cost = cb + (1.0f - giou);
    return ((u64)__float_as_uint(cost) << 32) | (unsigned)p;
}

__global__ __launch_bounds__(256) void matcher_topk_kernel(
    const float* __restrict__ pred_box,  // [B, NP, 4]
    const float* __restrict__ gt_box,    // [B, NG, 4]
    int* __restrict__ out_pred,          // [B, NG*TOPK]
    int* __restrict__ out_gt,            // [B, NG*TOPK]
    int B, int NP, int NG)
{
    const int task = blockIdx.x;              // one block per (b, m)
    const int t    = threadIdx.x;
    const int wid  = t >> 6;
    const int lane = t & 63;
    const int b = task / NG;
    const int m = task - b * NG;

    const float4 gb = ((const float4*)gt_box)[b * NG + m];
    const float g_area = (gb.z - gb.x) * (gb.w - gb.y);

    __shared__ float4 sbuf[2][CHUNK];
    __shared__ u64 smerge[WAVES][TOPK];

    const float4* pbase = (const float4*)pred_box + (size_t)b * NP;
    const int NPm1  = NP - 1;
    const int NITER = (NP + CHUNK - 1) / CHUNK;   // 5 for NP=5000

    u64 k0 = ~0ULL, k1 = ~0ULL, k2 = ~0ULL, k3 = ~0ULL, k4 = ~0ULL;
    unsigned thr_u = 0xFFFFFFFFu;                 // u32 view of k4's cost

    // prologue: stage chunk 0
    {
        float4 r0 = pbase[min(t,       NPm1)];
        float4 r1 = pbase[min(t + 256, NPm1)];
        float4 r2 = pbase[min(t + 512, NPm1)];
        float4 r3 = pbase[min(t + 768, NPm1)];
        sbuf[0][t]       = r0;
        sbuf[0][t + 256] = r1;
        sbuf[0][t + 512] = r2;
        sbuf[0][t + 768] = r3;
    }
    __syncthreads();

#define PROC1(pb_, idx_) do {                                            \
    const float _cb = fabsf(pb_.x - gb.x) + fabsf(pb_.y - gb.y)          \
                    + fabsf(pb_.z - gb.z) + fabsf(pb_.w - gb.w);         \
    const bool _valid = (idx_) < NP;                                     \
    const bool _want = (__float_as_uint(_cb) < thr_u) && _valid;         \
    if (__any((int)_want)) {                                             \
        u64 _k = eval_rest(pb_, _cb, gb, g_area, (idx_));                \
        _k = _valid ? _k : ~0ULL;                                        \
        INSERT(_k, k0, k1, k2, k3, k4);                                  \
        thr_u = (unsigned)(k4 >> 32);                                    \
    }                                                                    \
} while (0)

    int cur = 0;
    for (int it = 0; it < NITER; ++it) {
        // issue next chunk's global loads FIRST (consumed only by the
        // ds_write after this iteration's compute -> latency hidden)
        float4 r0, r1, r2, r3;
        const bool more = (it + 1 < NITER);
        if (more) {
            const int nb = (it + 1) * CHUNK + t;
            r0 = pbase[min(nb,       NPm1)];
            r1 = pbase[min(nb + 256, NPm1)];
            r2 = pbase[min(nb + 512, NPm1)];
            r3 = pbase[min(nb + 768, NPm1)];
        }
        asm volatile("" ::: "memory");   // keep loads above the compute

        // compute 4 candidates from staged chunk
        const int base = it * CHUNK + t;
        {
            const float4 p0 = sbuf[cur][t];
            PROC1(p0, base);
            const float4 p1 = sbuf[cur][t + 256];
            PROC1(p1, base + 256);
            const float4 p2 = sbuf[cur][t + 512];
            PROC1(p2, base + 512);
            const float4 p3 = sbuf[cur][t + 768];
            PROC1(p3, base + 768);
        }

        // stage next chunk into the OTHER buffer (safe: its readers finished
        // before the barrier at the end of the previous iteration)
        if (more) {
            sbuf[cur ^ 1][t]       = r0;
            sbuf[cur ^ 1][t + 256] = r1;
            sbuf[cur ^ 1][t + 512] = r2;
            sbuf[cur ^ 1][t + 768] = r3;
            cur ^= 1;
        }
        __syncthreads();
    }
#undef PROC1

    // wave butterfly: merge sorted 5-lists across all 64 lanes
    #pragma unroll
    for (int off = 1; off < 64; off <<= 1) {
        const u64 b0 = __shfl_xor(k0, off);
        const u64 b1 = __shfl_xor(k1, off);
        const u64 b2 = __shfl_xor(k2, off);
        const u64 b3 = __shfl_xor(k3, off);
        const u64 b4 = __shfl_xor(k4, off);
        u64 m0 = k0 < b4 ? k0 : b4;
        u64 m1 = k1 < b3 ? k1 : b3;
        u64 m2 = k2 < b2 ? k2 : b2;
        u64 m3 = k3 < b1 ? k3 : b1;
        u64 m4 = k4 < b0 ? k4 : b0;
        CE(m0, m1); CE(m3, m4); CE(m2, m4); CE(m2, m3); CE(m1, m4);
        CE(m0, m3); CE(m0, m2); CE(m1, m3); CE(m1, m2);
        k0 = m0; k1 = m1; k2 = m2; k3 = m3; k4 = m4;
    }

    // cross-wave merge via LDS (4 sorted 5-lists -> final 5)
    if (lane == 0) {
        smerge[wid][0] = k0; smerge[wid][1] = k1; smerge[wid][2] = k2;
        smerge[wid][3] = k3; smerge[wid][4] = k4;
    }
    __syncthreads();

    if (t == 0) {
        int head[WAVES];
        #pragma unroll
        for (int w = 0; w < WAVES; ++w) head[w] = 0;
        const int baseo = task * TOPK;
        #pragma unroll
        for (int r = 0; r < TOPK; ++r) {
            u64 best = ~0ULL; int bw = 0;
            #pragma unroll
            for (int w = 0; w < WAVES; ++w) {
                const u64 v = smerge[w][head[w]];
                if (v < best) { best = v; bw = w; }
            }
            head[bw]++;
            out_pred[baseo + r] = (int)(unsigned)(best & 0xFFFFFFFFu);
            out_gt[baseo + r]   = m;
        }
    }
}

extern "C" void kernel_launch(void* const* d_in, const int* in_sizes, int n_in,
                              void* d_out, int out_size, void* d_ws, size_t ws_size,
                              hipStream_t stream) {
    const float* pred_box = (const float*)d_in[0];   // [B, NP, 4]
    const float* gt_box   = (const float*)d_in[2];   // [B, NG, 4]

    const int NP = 5000;
    const int B  = in_sizes[1] / NP;                 // pred_obj is [B, NP]
    const int NG = in_sizes[3] / B;                  // gt_obj is [B, NG]

    int* out_pred = (int*)d_out;
    int* out_gt   = out_pred + B * NG * TOPK;

    const int total = B * NG;                        // one block per task
    hipLaunchKernelGGL(matcher_topk_kernel, dim3(total), dim3(256), 0, stream,
                       pred_box, gt_box, out_pred, out_gt, B, NP, NG);
}